// Round 2
// baseline (1189.652 us; speedup 1.0000x reference)
//
#include <hip/hip_runtime.h>
#include <hip/hip_bf16.h>

#define NN 50000
#define NE 800000
#define INC 64
#define HC 128
#define NC1 64
#define NC2 16

// ---- workspace layout (float offsets) ----
#define OFF_FLAG 0
// converted fp32 weights, contiguous, dst = 16 + i for cvt element i
#define OFW_W1R 16
#define OFW_W1O 8208
#define OFW_B1  16400
#define OFW_PW1 16528
#define OFW_PB1 24720
#define OFW_G1  24784
#define OFW_BE1 24848
#define OFW_W2R 24912
#define OFW_B2  41296
#define OFW_W2O 41424
#define OFW_PW2 57808
#define OFW_PB2 59856
#define OFW_G2  59872
#define OFW_BE2 59888
#define CVT_TOTAL 59888

#define OFF_MP   59920
#define OFF_X2   68112
#define OFF_XD   76320
#define OFF_X1   3276320
#define OFF_S    9676320
// ---- zeroed region start ----
#define OFF_DEN  12876320
#define OFF_PX   12876336
#define OFF_PADJ 12884528
#define OFF_STS  12888624
#define OFF_DEG  12892720
#define OFF_AGG  12942736
#define OFF_AS   16142736
#define OFF_END  19342736
#define ZERO_FLOATS (OFF_END - OFF_DEN)

__device__ inline float wave_sum(float v){
#pragma unroll
  for (int o = 32; o > 0; o >>= 1) v += __shfl_xor(v, o, 64);
  return v;
}
__device__ inline float wave_max(float v){
#pragma unroll
  for (int o = 32; o > 0; o >>= 1) v = fmaxf(v, __shfl_xor(v, o, 64));
  return v;
}

__device__ inline void store_out(void* out, long long idx, float v, bool bf){
  if (bf) ((__hip_bfloat16*)out)[idx] = __float2bfloat16(v);
  else    ((float*)out)[idx] = v;
}

// K0: detect input float dtype from drop_mask bit patterns.
// bf16 pairs: ~half of words are 0x3F803F80 or 0x00003F80 (impossible for fp32 0/1 data).
__global__ void k_detect(const unsigned int* __restrict__ dmw, float* __restrict__ flag){
  __shared__ int cnt;
  if (threadIdx.x == 0) cnt = 0;
  __syncthreads();
  int c = 0;
  for (int i = threadIdx.x; i < 12288; i += 256){   // 12288 words < 25000 (bf16 buf words)
    unsigned int w = dmw[i];
    if (w == 0x3F803F80u || w == 0x00003F80u) c++;
  }
  atomicAdd(&cnt, c);
  __syncthreads();
  if (threadIdx.x == 0) flag[0] = (cnt > 64) ? 1.0f : 0.0f;  // 1.0 => bf16 inputs
}

// K0b: convert all weight tensors to fp32 in ws (dst = 16 + i)
__global__ void k_cvt(const void* p0, const void* p1, const void* p2, const void* p3,
                      const void* p4, const void* p5, const void* p6, const void* p7,
                      const void* p8, const void* p9, const void* p10, const void* p11,
                      const void* p12, const void* p13,
                      const float* __restrict__ flag, float* __restrict__ ws){
  int i = blockIdx.x * blockDim.x + threadIdx.x;
  if (i >= CVT_TOTAL) return;
  const void* src; int off;
  if      (i < 8192 ){ src = p0;  off = i; }
  else if (i < 16384){ src = p1;  off = i - 8192; }
  else if (i < 16512){ src = p2;  off = i - 16384; }
  else if (i < 24704){ src = p3;  off = i - 16512; }
  else if (i < 24768){ src = p4;  off = i - 24704; }
  else if (i < 24832){ src = p5;  off = i - 24768; }
  else if (i < 24896){ src = p6;  off = i - 24832; }
  else if (i < 41280){ src = p7;  off = i - 24896; }
  else if (i < 41408){ src = p8;  off = i - 41280; }
  else if (i < 57792){ src = p9;  off = i - 41408; }
  else if (i < 59840){ src = p10; off = i - 57792; }
  else if (i < 59856){ src = p11; off = i - 59840; }
  else if (i < 59872){ src = p12; off = i - 59856; }
  else               { src = p13; off = i - 59872; }
  float v = (flag[0] > 0.5f) ? __bfloat162float(((const __hip_bfloat16*)src)[off])
                             : ((const float*)src)[off];
  ws[16 + i] = v;
}

// K1: x_drop = drop_mask[:,None] * x  -> fp32
__global__ void k_xdrop(const void* __restrict__ xr, const void* __restrict__ dmr,
                        const float* __restrict__ flag, float* __restrict__ xd){
  int i = blockIdx.x * blockDim.x + threadIdx.x;
  if (i >= NN * INC) return;
  int n = i >> 6;
  float xv, dv;
  if (flag[0] > 0.5f){
    xv = __bfloat162float(((const __hip_bfloat16*)xr)[i]);
    dv = __bfloat162float(((const __hip_bfloat16*)dmr)[n]);
  } else {
    xv = ((const float*)xr)[i];
    dv = ((const float*)dmr)[n];
  }
  xd[i] = xv * dv;
}

// K2a: deg[row[e]] += 1
__global__ void k_deg(const int* __restrict__ ei, float* __restrict__ deg){
  int e = blockIdx.x * blockDim.x + threadIdx.x;
  if (e < NE) atomicAdd(&deg[ei[e]], 1.0f);
}

// K2b: agg[col[e]][:] += x_drop[row[e]][:]   (one wave per edge)
__global__ void k_agg(const int* __restrict__ ei, const float* __restrict__ xd,
                      float* __restrict__ agg){
  int gid  = blockIdx.x * blockDim.x + threadIdx.x;
  int lane = gid & 63;
  int wid  = gid >> 6;
  int nw   = (gridDim.x * blockDim.x) >> 6;
  for (int e = wid; e < NE; e += nw){
    int r = ei[e];
    int c = ei[NE + e];
    float v = xd[(r << 6) + lane];
    if (v != 0.0f) atomicAdd(&agg[(c << 6) + lane], v);   // dropped rows skip entirely
  }
}

// K3: x1 = relu(agg @ W1_rel^T + b1 + x_drop @ W1_root^T)
// 128 threads/block, thread t owns output channel h=t; both weight rows in registers.
__global__ __launch_bounds__(128) void k_x1(const float* __restrict__ agg,
                                            const float* __restrict__ xd,
                                            const float* __restrict__ wts,
                                            float* __restrict__ x1){
  __shared__ float nb[4][2][INC];   // 4 nodes x {agg,xd} x 64
  int t = threadIdx.x;
  float wr[64], wo[64];
#pragma unroll
  for (int j = 0; j < 64; ++j){
    wr[j] = wts[OFW_W1R + t * 64 + j];
    wo[j] = wts[OFW_W1O + t * 64 + j];
  }
  float bias = wts[OFW_B1 + t];
  for (int n0 = blockIdx.x * 4; n0 < NN; n0 += gridDim.x * 4){
#pragma unroll
    for (int u = 0; u < 4; ++u){
      int node = n0 + u;
      int m = (t >> 6) & 1;
      int k = t & 63;
      nb[u][m][k] = m ? xd[(node << 6) + k] : agg[(node << 6) + k];
    }
    __syncthreads();
#pragma unroll
    for (int a = 0; a < 4; ++a){
      float acc = bias;
#pragma unroll
      for (int j = 0; j < 64; ++j)
        acc += nb[a][0][j] * wr[j] + nb[a][1][j] * wo[j];
      x1[(n0 + a) * HC + t] = fmaxf(acc, 0.0f);
    }
    __syncthreads();
  }
}

// K4: s1 = LN(x1 @ pW1^T + pb1); s=softmax fp32, ls1=log_softmax to out,
//     den += deg[n]*||s_n||^2. One wave per node.
__global__ __launch_bounds__(256) void k_s1(const float* __restrict__ x1,
                                            const float* __restrict__ wts,
                                            const float* __restrict__ deg,
                                            float* __restrict__ s,
                                            void* __restrict__ outp,
                                            const float* __restrict__ flag,
                                            float* __restrict__ den){
  __shared__ float pw[NC1 * 129];   // fp32, padded stride 129
  __shared__ float pb[NC1], gg[NC1], bb[NC1];
  __shared__ float wden[4];
  int t = threadIdx.x;
  for (int i = t; i < NC1 * HC; i += 256){
    int c = i >> 7, kk = i & 127;
    pw[c * 129 + kk] = wts[OFW_PW1 + i];
  }
  if (t < NC1){
    pb[t] = wts[OFW_PB1 + t];
    gg[t] = wts[OFW_G1 + t];
    bb[t] = wts[OFW_BE1 + t];
  }
  bool bf = flag[0] > 0.5f;
  int lane = t & 63, wv = t >> 6;
  float dacc = 0.0f;
  __syncthreads();
  for (int n = blockIdx.x * 4 + wv; n < NN; n += gridDim.x * 4){
    const float* xr = x1 + n * HC;
    float acc = pb[lane];
#pragma unroll
    for (int kk = 0; kk < HC; ++kk)
      acc += xr[kk] * pw[lane * 129 + kk];
    float mu  = wave_sum(acc) * (1.0f / 64.0f);
    float d   = acc - mu;
    float var = wave_sum(d * d) * (1.0f / 64.0f);
    float y   = d * rsqrtf(var + 1e-5f) * gg[lane] + bb[lane];
    float m   = wave_max(y);
    float ex  = expf(y - m);
    float se  = wave_sum(ex);
    float sv  = ex / se;
    s[n * NC1 + lane] = sv;
    store_out(outp, 4LL + (long long)n * NC1 + lane, (y - m) - logf(se), bf);
    dacc += deg[n] * sv * sv;
  }
  float wsum = wave_sum(dacc);
  if (lane == 0) wden[wv] = wsum;
  __syncthreads();
  if (t == 0) atomicAdd(den, wden[0] + wden[1] + wden[2] + wden[3]);
}

// K5: A_s[row[e]][:] += s[col[e]][:]
__global__ void k_As(const int* __restrict__ ei, const float* __restrict__ s,
                     float* __restrict__ A_s){
  int gid  = blockIdx.x * blockDim.x + threadIdx.x;
  int lane = gid & 63;
  int wid  = gid >> 6;
  int nw   = (gridDim.x * blockDim.x) >> 6;
  for (int e = wid; e < NE; e += nw){
    int r = ei[e];
    int c = ei[NE + e];
    atomicAdd(&A_s[(r << 6) + lane], s[(c << 6) + lane]);
  }
}

// K6: pooled_x = s^T x1, pooled_adj = s^T A_s, sTs = s^T s
__global__ __launch_bounds__(256) void k_pool(const float* __restrict__ s,
                                              const float* __restrict__ x1,
                                              const float* __restrict__ A_s,
                                              float* __restrict__ px,
                                              float* __restrict__ padj,
                                              float* __restrict__ sts){
  __shared__ float ssh[NC1], xsh[HC], ash[NC1];
  int t = threadIdx.x;
  int c = t >> 2, q = t & 3;
  float apx[32], apa[16], ast[16];
#pragma unroll
  for (int j = 0; j < 32; ++j) apx[j] = 0.0f;
#pragma unroll
  for (int j = 0; j < 16; ++j){ apa[j] = 0.0f; ast[j] = 0.0f; }
  for (int n = blockIdx.x; n < NN; n += gridDim.x){
    if (t < 64)       ssh[t]       = s[n * NC1 + t];
    else if (t < 192) xsh[t - 64]  = x1[n * HC + (t - 64)];
    else              ash[t - 192] = A_s[n * NC1 + (t - 192)];
    __syncthreads();
    float sv = ssh[c];
#pragma unroll
    for (int j = 0; j < 32; ++j) apx[j] += sv * xsh[q + 4 * j];
#pragma unroll
    for (int j = 0; j < 16; ++j) apa[j] += sv * ash[q + 4 * j];
#pragma unroll
    for (int j = 0; j < 16; ++j) ast[j] += sv * ssh[q + 4 * j];
    __syncthreads();
  }
#pragma unroll
  for (int j = 0; j < 32; ++j) atomicAdd(&px[c * HC + q + 4 * j], apx[j]);
#pragma unroll
  for (int j = 0; j < 16; ++j) atomicAdd(&padj[c * NC1 + q + 4 * j], apa[j]);
#pragma unroll
  for (int j = 0; j < 16; ++j) atomicAdd(&sts[c * NC1 + q + 4 * j], ast[j]);
}

__device__ inline float block_reduce_1024(float v, float* red, int t){
  red[t] = v; __syncthreads();
#pragma unroll
  for (int sh = 512; sh > 0; sh >>= 1){
    if (t < sh) red[t] += red[t + sh];
    __syncthreads();
  }
  float r = red[0];
  __syncthreads();
  return r;
}

// K7: pooled-graph tail (single block, 1024 threads)
__global__ __launch_bounds__(1024) void k_final(const float* __restrict__ px,
                                                const float* __restrict__ padj,
                                                const float* __restrict__ sts,
                                                const float* __restrict__ den_g,
                                                const float* __restrict__ wts,
                                                float* __restrict__ mp_ws,
                                                float* __restrict__ x2_ws,
                                                void* __restrict__ out,
                                                const float* __restrict__ flag){
  __shared__ float red[1024];
  __shared__ float Msh[NC1 * NC1];
  __shared__ float dsi[NC1];
  __shared__ float s2[NC1 * NC2];
  __shared__ float a2[NC1 * NC2];
  __shared__ float deg2[NC1];
  __shared__ float sts2[NC2 * NC2];
  const int t = threadIdx.x;
  const float TH = 1.0f / 63.0f;
  bool bf = flag[0] > 0.5f;

  // mc1 numerator: trace(pooled_adj)
  float v = (t < 64) ? padj[t * 65] : 0.0f;
  float num1 = block_reduce_1024(v, red, t);

  // o1
  v = 0.0f;
  for (int i = t; i < 4096; i += 1024){ float e = sts[i]; v += e * e; }
  float nrm1 = sqrtf(block_reduce_1024(v, red, t));
  v = 0.0f;
  for (int i = t; i < 4096; i += 1024){
    float e = sts[i] / (nrm1 + 1e-10f) - ((i % 65 == 0) ? 0.125f : 0.0f);
    v += e * e;
  }
  float o1 = sqrtf(block_reduce_1024(v, red, t));

  // adj (diag 0) row sums -> dsi
  if (t < 64){
    float rs = 0.0f;
    for (int j = 0; j < 64; ++j) rs += (j == t) ? 0.0f : padj[t * 64 + j];
    dsi[t] = 1.0f / (sqrtf(rs) + 1e-15f);
  }
  __syncthreads();
  // M = (adj_norm > TH)
  for (int i = t; i < 4096; i += 1024){
    int r = i >> 6, c = i & 63;
    float a = (r == c) ? 0.0f : padj[i];
    Msh[i] = (a * dsi[r] * dsi[c] > TH) ? 1.0f : 0.0f;
  }
  __syncthreads();
  // mp = M^T @ px
  for (int o = t; o < 8192; o += 1024){
    int c = o >> 7, f = o & 127;
    float acc = 0.0f;
    for (int i = 0; i < 64; ++i) acc += Msh[i * 64 + c] * px[i * 128 + f];
    mp_ws[o] = acc;
  }
  __syncthreads();
  // x2 = relu(mp @ W2_rel^T + b2 + px @ W2_root^T)
  for (int o = t; o < 8192; o += 1024){
    int c = o >> 7, f = o & 127;
    float acc = wts[OFW_B2 + f];
    const float* wrr = wts + OFW_W2R + f * 128;
    const float* wor = wts + OFW_W2O + f * 128;
    const float* mpr = mp_ws + c * 128;
    const float* pxr = px + c * 128;
    for (int k = 0; k < 128; ++k)
      acc += mpr[k] * wrr[k] + pxr[k] * wor[k];
    x2_ws[o] = fmaxf(acc, 0.0f);
  }
  __syncthreads();
  // s2 logits + LN + softmax/log_softmax per row (t<64); deg2
  if (t < 64){
    float l[16];
    const float* xr = x2_ws + t * 128;
    for (int u = 0; u < NC2; ++u){
      float acc = wts[OFW_PB2 + u];
      const float* pw = wts + OFW_PW2 + u * 128;
      for (int k = 0; k < 128; ++k) acc += xr[k] * pw[k];
      l[u] = acc;
    }
    float mu = 0.0f;
    for (int u = 0; u < NC2; ++u) mu += l[u];
    mu *= (1.0f / NC2);
    float var = 0.0f;
    for (int u = 0; u < NC2; ++u){ float d = l[u] - mu; var += d * d; }
    var *= (1.0f / NC2);
    float rstd = rsqrtf(var + 1e-5f);
    float m = -3.4e38f;
    for (int u = 0; u < NC2; ++u){
      l[u] = (l[u] - mu) * rstd * wts[OFW_G2 + u] + wts[OFW_BE2 + u];
      m = fmaxf(m, l[u]);
    }
    float se = 0.0f;
    for (int u = 0; u < NC2; ++u) se += expf(l[u] - m);
    float lse = logf(se);
    for (int u = 0; u < NC2; ++u){
      store_out(out, 4LL + (long long)NN * NC1 + t * NC2 + u, l[u] - m - lse, bf);
      s2[t * NC2 + u] = expf(l[u] - m) / se;
    }
    float d2 = 0.0f;
    for (int j = 0; j < 64; ++j) d2 += Msh[t * 64 + j];
    deg2[t] = d2;
  }
  __syncthreads();
  // a2 = M @ s2
  {
    int c = t >> 4, u = t & 15;
    float acc = 0.0f;
    for (int j = 0; j < 64; ++j) acc += Msh[c * 64 + j] * s2[j * NC2 + u];
    a2[t] = acc;
  }
  __syncthreads();
  // mc2
  v = s2[t] * a2[t];
  float num2 = block_reduce_1024(v, red, t);
  v = deg2[t >> 4] * s2[t] * s2[t];
  float den2 = block_reduce_1024(v, red, t) + 1e-10f;
  // o2
  if (t < 256){
    int u = t >> 4, w = t & 15;
    float acc = 0.0f;
    for (int c2 = 0; c2 < 64; ++c2) acc += s2[c2 * NC2 + u] * s2[c2 * NC2 + w];
    sts2[t] = acc;
  }
  __syncthreads();
  v = (t < 256) ? sts2[t] * sts2[t] : 0.0f;
  float nrm2 = sqrtf(block_reduce_1024(v, red, t));
  v = 0.0f;
  if (t < 256){
    float e = sts2[t] / (nrm2 + 1e-10f) - (((t >> 4) == (t & 15)) ? 0.25f : 0.0f);
    v = e * e;
  }
  float o2 = sqrtf(block_reduce_1024(v, red, t));

  if (t == 0){
    float dv = den_g[0] + 1e-10f;
    store_out(out, 0, -num1 / dv, bf);
    store_out(out, 1, o1, bf);
    store_out(out, 2, -num2 / den2, bf);
    store_out(out, 3, o2, bf);
  }
}

extern "C" void kernel_launch(void* const* d_in, const int* in_sizes, int n_in,
                              void* d_out, int out_size, void* d_ws, size_t ws_size,
                              hipStream_t stream){
  const void* x    = d_in[0];
  const int*  ei   = (const int*)d_in[1];
  const void* dm   = d_in[2];

  float* ws   = (float*)d_ws;
  float* flag = ws + OFF_FLAG;
  float* xd   = ws + OFF_XD;
  float* x1   = ws + OFF_X1;
  float* s    = ws + OFF_S;
  float* agg  = ws + OFF_AGG;
  float* A_s  = ws + OFF_AS;
  float* deg  = ws + OFF_DEG;
  float* px   = ws + OFF_PX;
  float* padj = ws + OFF_PADJ;
  float* sts  = ws + OFF_STS;
  float* den  = ws + OFF_DEN;
  float* mp   = ws + OFF_MP;
  float* x2   = ws + OFF_X2;

  hipMemsetAsync(ws + OFF_DEN, 0, (size_t)ZERO_FLOATS * sizeof(float), stream);

  k_detect<<<1, 256, 0, stream>>>((const unsigned int*)dm, flag);
  k_cvt<<<(CVT_TOTAL + 255) / 256, 256, 0, stream>>>(
      d_in[3], d_in[5], d_in[4], d_in[6], d_in[7], d_in[8], d_in[9],
      d_in[10], d_in[11], d_in[12], d_in[13], d_in[14], d_in[15], d_in[16],
      flag, ws);
  k_xdrop<<<(NN * INC + 255) / 256, 256, 0, stream>>>(x, dm, flag, xd);
  k_deg<<<(NE + 255) / 256, 256, 0, stream>>>(ei, deg);
  k_agg<<<4096, 256, 0, stream>>>(ei, xd, agg);
  k_x1<<<2048, 128, 0, stream>>>(agg, xd, ws, x1);
  k_s1<<<2048, 256, 0, stream>>>(x1, ws, deg, s, d_out, flag, den);
  k_As<<<4096, 256, 0, stream>>>(ei, s, A_s);
  k_pool<<<512, 256, 0, stream>>>(s, x1, A_s, px, padj, sts);
  k_final<<<1, 1024, 0, stream>>>(px, padj, sts, den, ws, mp, x2, d_out, flag);
}

// Round 3
// 870.575 us; speedup vs baseline: 1.3665x; 1.3665x over previous
//
#include <hip/hip_runtime.h>
#include <hip/hip_bf16.h>

#define NN 50000
#define NE 800000
#define INC 64
#define HC 128
#define NC1 64
#define NC2 16

// ---- workspace layout (float offsets) ----
#define OFF_FLAG 0
// converted fp32 weights, contiguous, dst = 16 + i for cvt element i
#define OFW_W1R 16
#define OFW_W1O 8208
#define OFW_B1  16400
#define OFW_PW1 16528
#define OFW_PB1 24720
#define OFW_G1  24784
#define OFW_BE1 24848
#define OFW_W2R 24912
#define OFW_B2  41296
#define OFW_W2O 41424
#define OFW_PW2 57808
#define OFW_PB2 59856
#define OFW_G2  59872
#define OFW_BE2 59888
#define CVT_TOTAL 59888

#define OFF_MG   59904
#define OFF_MTG  64000
#define OFF_DEG2 68096
#define OFF_S2G  68160
#define OFF_XD   69184
#define OFF_X1   3269184
#define OFF_S    9669184
// ---- zeroed region ----
#define OFF_SCAL 12869184
#define OFF_PX   12869200
#define OFF_PADJ 12877392
#define OFF_STS  12881488
#define OFF_DEG  12885584
#define OFF_AGG  12935584
#define OFF_END  16135584
#define ZERO_FLOATS (OFF_END - OFF_SCAL)

__device__ inline float wave_sum(float v){
#pragma unroll
  for (int o = 32; o > 0; o >>= 1) v += __shfl_xor(v, o, 64);
  return v;
}
__device__ inline float wave_max(float v){
#pragma unroll
  for (int o = 32; o > 0; o >>= 1) v = fmaxf(v, __shfl_xor(v, o, 64));
  return v;
}

__device__ inline void store_out(void* out, long long idx, float v, bool bf){
  if (bf) ((__hip_bfloat16*)out)[idx] = __float2bfloat16(v);
  else    ((float*)out)[idx] = v;
}

__device__ inline float block_reduce_256(float v, float* red, int t){
  red[t] = v; __syncthreads();
#pragma unroll
  for (int sh = 128; sh > 0; sh >>= 1){
    if (t < sh) red[t] += red[t + sh];
    __syncthreads();
  }
  float r = red[0];
  __syncthreads();
  return r;
}

// K0: detect input float dtype from drop_mask bit patterns.
__global__ void k_detect(const unsigned int* __restrict__ dmw, float* __restrict__ flag){
  __shared__ int cnt;
  if (threadIdx.x == 0) cnt = 0;
  __syncthreads();
  int c = 0;
  for (int i = threadIdx.x; i < 12288; i += 256){
    unsigned int w = dmw[i];
    if (w == 0x3F803F80u || w == 0x00003F80u) c++;
  }
  atomicAdd(&cnt, c);
  __syncthreads();
  if (threadIdx.x == 0) flag[0] = (cnt > 64) ? 1.0f : 0.0f;  // 1.0 => bf16 inputs
}

// K0b: convert all weight tensors to fp32 in ws (dst = 16 + i)
__global__ void k_cvt(const void* p0, const void* p1, const void* p2, const void* p3,
                      const void* p4, const void* p5, const void* p6, const void* p7,
                      const void* p8, const void* p9, const void* p10, const void* p11,
                      const void* p12, const void* p13,
                      const float* __restrict__ flag, float* __restrict__ ws){
  int i = blockIdx.x * blockDim.x + threadIdx.x;
  if (i >= CVT_TOTAL) return;
  const void* src; int off;
  if      (i < 8192 ){ src = p0;  off = i; }
  else if (i < 16384){ src = p1;  off = i - 8192; }
  else if (i < 16512){ src = p2;  off = i - 16384; }
  else if (i < 24704){ src = p3;  off = i - 16512; }
  else if (i < 24768){ src = p4;  off = i - 24704; }
  else if (i < 24832){ src = p5;  off = i - 24768; }
  else if (i < 24896){ src = p6;  off = i - 24832; }
  else if (i < 41280){ src = p7;  off = i - 24896; }
  else if (i < 41408){ src = p8;  off = i - 41280; }
  else if (i < 57792){ src = p9;  off = i - 41408; }
  else if (i < 59840){ src = p10; off = i - 57792; }
  else if (i < 59856){ src = p11; off = i - 59840; }
  else if (i < 59872){ src = p12; off = i - 59856; }
  else               { src = p13; off = i - 59872; }
  float v = (flag[0] > 0.5f) ? __bfloat162float(((const __hip_bfloat16*)src)[off])
                             : ((const float*)src)[off];
  ws[16 + i] = v;
}

// K1: x_drop = drop_mask[:,None] * x  -> fp32
__global__ void k_xdrop(const void* __restrict__ xr, const void* __restrict__ dmr,
                        const float* __restrict__ flag, float* __restrict__ xd){
  int i = blockIdx.x * blockDim.x + threadIdx.x;
  if (i >= NN * INC) return;
  int n = i >> 6;
  float xv, dv;
  if (flag[0] > 0.5f){
    xv = __bfloat162float(((const __hip_bfloat16*)xr)[i]);
    dv = __bfloat162float(((const __hip_bfloat16*)dmr)[n]);
  } else {
    xv = ((const float*)xr)[i];
    dv = ((const float*)dmr)[n];
  }
  xd[i] = xv * dv;
}

// K2a: deg[row[e]] += 1
__global__ void k_deg(const int* __restrict__ ei, float* __restrict__ deg){
  int e = blockIdx.x * blockDim.x + threadIdx.x;
  if (e < NE) atomicAdd(&deg[ei[e]], 1.0f);
}

// K2b: agg[col[e]][:] += x_drop[row[e]][:]   (one wave per edge)
__global__ void k_agg(const int* __restrict__ ei, const float* __restrict__ xd,
                      float* __restrict__ agg){
  int gid  = blockIdx.x * blockDim.x + threadIdx.x;
  int lane = gid & 63;
  int wid  = gid >> 6;
  int nw   = (gridDim.x * blockDim.x) >> 6;
  for (int e = wid; e < NE; e += nw){
    int r = ei[e];
    int c = ei[NE + e];
    float v = xd[(r << 6) + lane];
    if (v != 0.0f) atomicAdd(&agg[(c << 6) + lane], v);   // dropped rows skip entirely
  }
}

// K3: x1 = relu(agg @ W1_rel^T + b1 + x_drop @ W1_root^T)
__global__ __launch_bounds__(128) void k_x1(const float* __restrict__ agg,
                                            const float* __restrict__ xd,
                                            const float* __restrict__ wts,
                                            float* __restrict__ x1){
  __shared__ float nb[4][2][INC];
  int t = threadIdx.x;
  float wr[64], wo[64];
#pragma unroll
  for (int j = 0; j < 64; ++j){
    wr[j] = wts[OFW_W1R + t * 64 + j];
    wo[j] = wts[OFW_W1O + t * 64 + j];
  }
  float bias = wts[OFW_B1 + t];
  for (int n0 = blockIdx.x * 4; n0 < NN; n0 += gridDim.x * 4){
#pragma unroll
    for (int u = 0; u < 4; ++u){
      int node = n0 + u;
      int m = (t >> 6) & 1;
      int k = t & 63;
      nb[u][m][k] = m ? xd[(node << 6) + k] : agg[(node << 6) + k];
    }
    __syncthreads();
#pragma unroll
    for (int a = 0; a < 4; ++a){
      float acc = bias;
#pragma unroll
      for (int j = 0; j < 64; ++j)
        acc += nb[a][0][j] * wr[j] + nb[a][1][j] * wo[j];
      x1[(n0 + a) * HC + t] = fmaxf(acc, 0.0f);
    }
    __syncthreads();
  }
}

// K4: s1 = LN(x1 @ pW1^T + pb1); s=softmax fp32, ls1=log_softmax to out,
//     den += deg[n]*||s_n||^2. One wave per node.
__global__ __launch_bounds__(256) void k_s1(const float* __restrict__ x1,
                                            const float* __restrict__ wts,
                                            const float* __restrict__ deg,
                                            float* __restrict__ s,
                                            void* __restrict__ outp,
                                            const float* __restrict__ flag,
                                            float* __restrict__ scal){
  __shared__ float pw[NC1 * 129];
  __shared__ float pb[NC1], gg[NC1], bb[NC1];
  __shared__ float wden[4];
  int t = threadIdx.x;
  for (int i = t; i < NC1 * HC; i += 256){
    int c = i >> 7, kk = i & 127;
    pw[c * 129 + kk] = wts[OFW_PW1 + i];
  }
  if (t < NC1){
    pb[t] = wts[OFW_PB1 + t];
    gg[t] = wts[OFW_G1 + t];
    bb[t] = wts[OFW_BE1 + t];
  }
  bool bf = flag[0] > 0.5f;
  int lane = t & 63, wv = t >> 6;
  float dacc = 0.0f;
  __syncthreads();
  for (int n = blockIdx.x * 4 + wv; n < NN; n += gridDim.x * 4){
    const float* xr = x1 + n * HC;
    float acc = pb[lane];
#pragma unroll
    for (int kk = 0; kk < HC; ++kk)
      acc += xr[kk] * pw[lane * 129 + kk];
    float mu  = wave_sum(acc) * (1.0f / 64.0f);
    float d   = acc - mu;
    float var = wave_sum(d * d) * (1.0f / 64.0f);
    float y   = d * rsqrtf(var + 1e-5f) * gg[lane] + bb[lane];
    float m   = wave_max(y);
    float ex  = expf(y - m);
    float se  = wave_sum(ex);
    float sv  = ex / se;
    s[n * NC1 + lane] = sv;
    store_out(outp, 4LL + (long long)n * NC1 + lane, (y - m) - logf(se), bf);
    dacc += deg[n] * sv * sv;
  }
  float wsum = wave_sum(dacc);
  if (lane == 0) wden[wv] = wsum;
  __syncthreads();
  if (t == 0) atomicAdd(&scal[0], wden[0] + wden[1] + wden[2] + wden[3]);
}

// K5 (NEW): pooled_adj = sum_e s[row_e] (x) s[col_e]  — no A_s scatter.
// 4x4 register tile per thread; 16-edge batches staged in LDS.
#define PADJ_B 16
__global__ __launch_bounds__(256) void k_padj(const int* __restrict__ ei,
                                              const float* __restrict__ s,
                                              float* __restrict__ padj){
  __shared__ int eidx[2][PADJ_B];
  __shared__ float rows[PADJ_B][2][64];
  int t = threadIdx.x;
  int i4 = (t >> 4) << 2;
  int j4 = (t & 15) << 2;
  float acc[16];
#pragma unroll
  for (int m = 0; m < 16; ++m) acc[m] = 0.0f;
  const int nbatch = NE / PADJ_B;   // 50000
  for (int b = blockIdx.x; b < nbatch; b += gridDim.x){
    int e0 = b * PADJ_B;
    if (t < 32){
      int k = t & 15;
      eidx[t >> 4][k] = ei[((t < 16) ? 0 : NE) + e0 + k];
    }
    __syncthreads();
#pragma unroll
    for (int u = 0; u < 8; ++u){
      int f = t + (u << 8);
      int k = f >> 7, h = (f >> 6) & 1, l = f & 63;
      rows[k][h][l] = s[(eidx[h][k] << 6) + l];
    }
    __syncthreads();
#pragma unroll
    for (int k = 0; k < PADJ_B; ++k){
      float4 a  = *(const float4*)&rows[k][0][i4];
      float4 bb = *(const float4*)&rows[k][1][j4];
      acc[0]  += a.x * bb.x; acc[1]  += a.x * bb.y; acc[2]  += a.x * bb.z; acc[3]  += a.x * bb.w;
      acc[4]  += a.y * bb.x; acc[5]  += a.y * bb.y; acc[6]  += a.y * bb.z; acc[7]  += a.y * bb.w;
      acc[8]  += a.z * bb.x; acc[9]  += a.z * bb.y; acc[10] += a.z * bb.z; acc[11] += a.z * bb.w;
      acc[12] += a.w * bb.x; acc[13] += a.w * bb.y; acc[14] += a.w * bb.z; acc[15] += a.w * bb.w;
    }
    __syncthreads();
  }
#pragma unroll
  for (int m = 0; m < 16; ++m){
    int r = i4 + (m >> 2), c = j4 + (m & 3);
    atomicAdd(&padj[r * 64 + c], acc[m]);
  }
}

// K6: pooled_x = s^T x1, sTs = s^T s
__global__ __launch_bounds__(256) void k_pool(const float* __restrict__ s,
                                              const float* __restrict__ x1,
                                              float* __restrict__ px,
                                              float* __restrict__ sts){
  __shared__ float ssh[NC1], xsh[HC];
  int t = threadIdx.x;
  int c = t >> 2, q = t & 3;
  float apx[32], ast[16];
#pragma unroll
  for (int j = 0; j < 32; ++j) apx[j] = 0.0f;
#pragma unroll
  for (int j = 0; j < 16; ++j) ast[j] = 0.0f;
  for (int n = blockIdx.x; n < NN; n += gridDim.x){
    if (t < 64)       ssh[t]      = s[n * NC1 + t];
    else if (t < 192) xsh[t - 64] = x1[n * HC + (t - 64)];
    __syncthreads();
    float sv = ssh[c];
#pragma unroll
    for (int j = 0; j < 32; ++j) apx[j] += sv * xsh[q + 4 * j];
#pragma unroll
    for (int j = 0; j < 16; ++j) ast[j] += sv * ssh[q + 4 * j];
    __syncthreads();
  }
#pragma unroll
  for (int j = 0; j < 32; ++j) atomicAdd(&px[c * HC + q + 4 * j], apx[j]);
#pragma unroll
  for (int j = 0; j < 16; ++j) atomicAdd(&sts[c * NC1 + q + 4 * j], ast[j]);
}

// K7a: M, Mt, deg2, num1(trace), o1 — small stats (1 block)
__global__ __launch_bounds__(256) void k_m(const float* __restrict__ padj,
                                           const float* __restrict__ sts,
                                           float* __restrict__ Mg,
                                           float* __restrict__ Mtg,
                                           float* __restrict__ deg2,
                                           float* __restrict__ scal){
  __shared__ float red[256];
  __shared__ float psh[4096];
  __shared__ float dsi[64];
  int t = threadIdx.x;
  const float TH = 1.0f / 63.0f;
  for (int i = t; i < 4096; i += 256) psh[i] = padj[i];
  __syncthreads();
  float v = (t < 64) ? psh[t * 65] : 0.0f;
  float num1 = block_reduce_256(v, red, t);
  v = 0.0f;
  for (int i = t; i < 4096; i += 256){ float e = sts[i]; v += e * e; }
  float nrm1 = sqrtf(block_reduce_256(v, red, t));
  v = 0.0f;
  for (int i = t; i < 4096; i += 256){
    float e = sts[i] / (nrm1 + 1e-10f) - ((i % 65 == 0) ? 0.125f : 0.0f);
    v += e * e;
  }
  float o1 = sqrtf(block_reduce_256(v, red, t));
  if (t < 64){
    float rs = 0.0f;
    for (int j = 0; j < 64; ++j) rs += (j == t) ? 0.0f : psh[t * 64 + j];
    dsi[t] = 1.0f / (sqrtf(rs) + 1e-15f);
  }
  __syncthreads();
  for (int i = t; i < 4096; i += 256){
    int r = i >> 6, c = i & 63;
    float a = (r == c) ? 0.0f : psh[i];
    float m = (a * dsi[r] * dsi[c] > TH) ? 1.0f : 0.0f;
    Mg[i] = m;
    Mtg[c * 64 + r] = m;
  }
  __syncthreads();
  for (int i = t; i < 4096; i += 256){
    int r = i >> 6, c = i & 63;
    float a = (r == c) ? 0.0f : psh[i];
    psh[i] = (a * dsi[r] * dsi[c] > TH) ? 1.0f : 0.0f;
  }
  __syncthreads();
  if (t < 64){
    float d2 = 0.0f;
    for (int j = 0; j < 64; ++j) d2 += psh[t * 64 + j];
    deg2[t] = d2;
  }
  if (t == 0){ scal[1] = num1; scal[2] = o1; }
}

// K7b: per-cluster fused mp/x2/s2-logits/LN/softmax (64 blocks x 128 thr)
__global__ __launch_bounds__(128) void k_x2(const float* __restrict__ Mtg,
                                            const float* __restrict__ px,
                                            const float* __restrict__ wts,
                                            float* __restrict__ s2g,
                                            void* __restrict__ out,
                                            const float* __restrict__ flag){
  __shared__ float mt[64], pxc[128], mpsh[128], x2sh[128];
  __shared__ float part[16][9], lsh[16], stat[2];
  int c = blockIdx.x, t = threadIdx.x;
  if (t < 64) mt[t] = Mtg[c * 64 + t];
  pxc[t] = px[c * 128 + t];
  __syncthreads();
  float mp = 0.0f;
  for (int i = 0; i < 64; ++i) mp += mt[i] * px[i * 128 + t];
  mpsh[t] = mp;
  __syncthreads();
  float acc = wts[OFW_B2 + t];
  const float* wrr = wts + OFW_W2R + t * 128;
  const float* wor = wts + OFW_W2O + t * 128;
  for (int k = 0; k < 128; ++k) acc += mpsh[k] * wrr[k] + pxc[k] * wor[k];
  x2sh[t] = fmaxf(acc, 0.0f);
  __syncthreads();
  { int u = t >> 3, p = t & 7;
    const float* pw = wts + OFW_PW2 + u * 128 + p * 16;
    float pa = 0.0f;
    for (int k = 0; k < 16; ++k) pa += x2sh[p * 16 + k] * pw[k];
    part[u][p] = pa;
  }
  __syncthreads();
  if (t < 16){
    float l = wts[OFW_PB2 + t];
    for (int p = 0; p < 8; ++p) l += part[t][p];
    lsh[t] = l;
  }
  __syncthreads();
  if (t == 0){
    float mu = 0.0f;
    for (int u = 0; u < 16; ++u) mu += lsh[u];
    mu *= (1.0f / 16.0f);
    float var = 0.0f;
    for (int u = 0; u < 16; ++u){ float d = lsh[u] - mu; var += d * d; }
    var *= (1.0f / 16.0f);
    float rstd = rsqrtf(var + 1e-5f);
    float m = -3.4e38f;
    for (int u = 0; u < 16; ++u){
      lsh[u] = (lsh[u] - mu) * rstd * wts[OFW_G2 + u] + wts[OFW_BE2 + u];
      m = fmaxf(m, lsh[u]);
    }
    float se = 0.0f;
    for (int u = 0; u < 16; ++u) se += expf(lsh[u] - m);
    stat[0] = m; stat[1] = logf(se);
  }
  __syncthreads();
  if (t < 16){
    float ls = (lsh[t] - stat[0]) - stat[1];
    store_out(out, 4LL + (long long)NN * NC1 + c * 16 + t, ls, flag[0] > 0.5f);
    s2g[c * 16 + t] = expf(ls);
  }
}

// K7c: mc2 / o2 tail (1 block)
__global__ __launch_bounds__(256) void k_tail(const float* __restrict__ Mg,
                                              const float* __restrict__ s2g,
                                              const float* __restrict__ deg2,
                                              const float* __restrict__ scal,
                                              void* __restrict__ out,
                                              const float* __restrict__ flag){
  __shared__ float red[256];
  __shared__ float Msh[4096];
  __shared__ float s2sh[1024];
  __shared__ float d2sh[64];
  __shared__ float sts2[256];
  int t = threadIdx.x;
  for (int i = t; i < 4096; i += 256) Msh[i] = Mg[i];
  for (int i = t; i < 1024; i += 256) s2sh[i] = s2g[i];
  if (t < 64) d2sh[t] = deg2[t];
  __syncthreads();
  float vnum = 0.0f, vden = 0.0f;
  for (int m = 0; m < 4; ++m){
    int id = t + m * 256;
    int c = id >> 4, u = id & 15;
    float a = 0.0f;
    for (int j = 0; j < 64; ++j) a += Msh[c * 64 + j] * s2sh[j * 16 + u];
    float sv = s2sh[id];
    vnum += sv * a;
    vden += d2sh[c] * sv * sv;
  }
  float num2 = block_reduce_256(vnum, red, t);
  float den2 = block_reduce_256(vden, red, t) + 1e-10f;
  { int u = t >> 4, w = t & 15;
    float a = 0.0f;
    for (int c2 = 0; c2 < 64; ++c2) a += s2sh[c2 * 16 + u] * s2sh[c2 * 16 + w];
    sts2[t] = a;
  }
  __syncthreads();
  float v = sts2[t] * sts2[t];
  float nrm2 = sqrtf(block_reduce_256(v, red, t));
  { float e = sts2[t] / (nrm2 + 1e-10f) - (((t >> 4) == (t & 15)) ? 0.25f : 0.0f);
    v = e * e; }
  float o2 = sqrtf(block_reduce_256(v, red, t));
  if (t == 0){
    bool bf = flag[0] > 0.5f;
    float den = scal[0] + 1e-10f;
    store_out(out, 0, -scal[1] / den, bf);
    store_out(out, 1, scal[2], bf);
    store_out(out, 2, -num2 / den2, bf);
    store_out(out, 3, o2, bf);
  }
}

extern "C" void kernel_launch(void* const* d_in, const int* in_sizes, int n_in,
                              void* d_out, int out_size, void* d_ws, size_t ws_size,
                              hipStream_t stream){
  const void* x  = d_in[0];
  const int*  ei = (const int*)d_in[1];
  const void* dm = d_in[2];

  float* ws   = (float*)d_ws;
  float* flag = ws + OFF_FLAG;
  float* xd   = ws + OFF_XD;
  float* x1   = ws + OFF_X1;
  float* s    = ws + OFF_S;
  float* agg  = ws + OFF_AGG;
  float* deg  = ws + OFF_DEG;
  float* px   = ws + OFF_PX;
  float* padj = ws + OFF_PADJ;
  float* sts  = ws + OFF_STS;
  float* scal = ws + OFF_SCAL;
  float* Mg   = ws + OFF_MG;
  float* Mtg  = ws + OFF_MTG;
  float* deg2 = ws + OFF_DEG2;
  float* s2g  = ws + OFF_S2G;

  hipMemsetAsync(ws + OFF_SCAL, 0, (size_t)ZERO_FLOATS * sizeof(float), stream);

  k_detect<<<1, 256, 0, stream>>>((const unsigned int*)dm, flag);
  k_cvt<<<(CVT_TOTAL + 255) / 256, 256, 0, stream>>>(
      d_in[3], d_in[5], d_in[4], d_in[6], d_in[7], d_in[8], d_in[9],
      d_in[10], d_in[11], d_in[12], d_in[13], d_in[14], d_in[15], d_in[16],
      flag, ws);
  k_xdrop<<<(NN * INC + 255) / 256, 256, 0, stream>>>(x, dm, flag, xd);
  k_deg<<<(NE + 255) / 256, 256, 0, stream>>>(ei, deg);
  k_agg<<<4096, 256, 0, stream>>>(ei, xd, agg);
  k_x1<<<2048, 128, 0, stream>>>(agg, xd, ws, x1);
  k_s1<<<2048, 256, 0, stream>>>(x1, ws, deg, s, d_out, flag, scal);
  k_padj<<<512, 256, 0, stream>>>(ei, s, padj);
  k_pool<<<512, 256, 0, stream>>>(s, x1, px, sts);
  k_m<<<1, 256, 0, stream>>>(padj, sts, Mg, Mtg, deg2, scal);
  k_x2<<<64, 128, 0, stream>>>(Mtg, px, ws, s2g, d_out, flag);
  k_tail<<<1, 256, 0, stream>>>(Mg, s2g, deg2, scal, d_out, flag);
}